// Round 3
// baseline (131.064 us; speedup 1.0000x reference)
//
#include <hip/hip_runtime.h>

// Problem constants (KANLayer): B=1024, I=128, O=128, H=5
#define Bsz 1024
#define Isz 128
#define Osz 128
#define Hsz 5
#define ICHUNK 16   // i-slice per block -> 8 partial-sum rounds per (b,o)
#define MB 4        // batch rows per thread (2x v2f pairs -> v_pk_fma_f32)

typedef float v2f __attribute__((ext_vector_type(2)));
__device__ __forceinline__ v2f s2(float v) { return (v2f){v, v}; }

// ---------------------------------------------------------------------------
// Single kernel (no repack prologue -- it serialized ~55us of wall time).
// Block = (o, i-chunk of 16); 256 threads; thread owns batch rows
// b = tid + 256k, k=0..3, packed as two v2f pairs so layer math lowers to
// v_pk_fma_f32. All param addresses depend only on (o,i) -> wave-uniform ->
// scalar loads (confirmed round 2: VGPR=24/SGPR=80).
// Grid = 128 o (fastest, shares x-slice in L1) x 8 ic = 1024 blocks.
// ---------------------------------------------------------------------------
__global__ __launch_bounds__(256, 4)
void kan_kernel(const float* __restrict__ x,
                const float* __restrict__ W1, const float* __restrict__ B1,
                const float* __restrict__ W2, const float* __restrict__ B2,
                const float* __restrict__ W3, const float* __restrict__ B3,
                float* __restrict__ out) {
    const int tid = threadIdx.x;
    const int o   = blockIdx.x & (Osz - 1);
    const int ic  = blockIdx.x >> 7;          // 0..7
    const int i0  = ic * ICHUNK;

    v2f acc0 = s2(0.0f);   // rows tid, tid+256
    v2f acc1 = s2(0.0f);   // rows tid+512, tid+768

    #pragma unroll
    for (int jj = 0; jj < ICHUNK / 4; ++jj) {
        // x for my 4 rows x 4 cols (16B loads; x is L2-resident, 512 KB total)
        float4 xq[MB];
        #pragma unroll
        for (int k = 0; k < MB; ++k)
            xq[k] = *(const float4*)(x + (size_t)(tid + 256 * k) * Isz + i0 + 4 * jj);
        const float* xf = (const float*)&xq[0];

        #pragma unroll
        for (int q = 0; q < 4; ++q) {
            const int e = o * Isz + i0 + 4 * jj + q;

            // Wave-uniform param fetch -> s_loads.
            float w1[Hsz], b1[Hsz], w2[Hsz * Hsz], b2[Hsz], w3[Hsz];
            #pragma unroll
            for (int h = 0; h < Hsz; ++h) {
                w1[h] = W1[e * Hsz + h];
                b1[h] = B1[e * Hsz + h];
                b2[h] = B2[e * Hsz + h];
                w3[h] = W3[e * Hsz + h];
            }
            #pragma unroll
            for (int j = 0; j < Hsz * Hsz; ++j) w2[j] = W2[e * Hsz * Hsz + j];
            const float b3v = B3[e];

            // a-pairs: xf layout = [k][4] floats
            const v2f a0 = {xf[0 * 4 + q], xf[1 * 4 + q]};
            const v2f a1 = {xf[2 * 4 + q], xf[3 * 4 + q]};

            // layer 1: scalar -> H, leaky_relu(0.01)
            v2f h10[Hsz], h11[Hsz];
            #pragma unroll
            for (int h = 0; h < Hsz; ++h) {
                const v2f wv = s2(w1[h]), bv = s2(b1[h]);
                v2f t0 = __builtin_elementwise_fma(a0, wv, bv);
                v2f t1 = __builtin_elementwise_fma(a1, wv, bv);
                h10[h] = __builtin_elementwise_max(t0, t0 * 0.01f);
                h11[h] = __builtin_elementwise_max(t1, t1 * 0.01f);
            }

            // layer 2 (H->H) + layer 3 (H->1)
            v2f y0 = s2(b3v), y1 = s2(b3v);
            #pragma unroll
            for (int k = 0; k < Hsz; ++k) {
                v2f s0 = s2(b2[k]), s1 = s2(b2[k]);
                #pragma unroll
                for (int h = 0; h < Hsz; ++h) {
                    const v2f wv = s2(w2[k * Hsz + h]);
                    s0 = __builtin_elementwise_fma(h10[h], wv, s0);
                    s1 = __builtin_elementwise_fma(h11[h], wv, s1);
                }
                s0 = __builtin_elementwise_max(s0, s0 * 0.01f);
                s1 = __builtin_elementwise_max(s1, s1 * 0.01f);
                const v2f w3v = s2(w3[k]);
                y0 = __builtin_elementwise_fma(s0, w3v, y0);
                y1 = __builtin_elementwise_fma(s1, w3v, y1);
            }
            acc0 += y0;
            acc1 += y1;
        }
    }

    // One fp32 atomic per owned row (out pre-zeroed by memset).
    atomicAdd(&out[(size_t)(tid +   0) * Osz + o], acc0.x);
    atomicAdd(&out[(size_t)(tid + 256) * Osz + o], acc0.y);
    atomicAdd(&out[(size_t)(tid + 512) * Osz + o], acc1.x);
    atomicAdd(&out[(size_t)(tid + 768) * Osz + o], acc1.y);
}

extern "C" void kernel_launch(void* const* d_in, const int* in_sizes, int n_in,
                              void* d_out, int out_size, void* d_ws, size_t ws_size,
                              hipStream_t stream) {
    const float* x  = (const float*)d_in[0];
    const float* W1 = (const float*)d_in[1];
    const float* B1 = (const float*)d_in[2];
    const float* W2 = (const float*)d_in[3];
    const float* B2 = (const float*)d_in[4];
    const float* W3 = (const float*)d_in[5];
    const float* B3 = (const float*)d_in[6];
    float* out = (float*)d_out;

    // out accumulates 8 i-chunk partials via atomicAdd -> must start at zero.
    hipMemsetAsync(out, 0, (size_t)out_size * sizeof(float), stream);

    const dim3 grid(Osz * (Isz / ICHUNK));  // 1024 blocks
    kan_kernel<<<grid, dim3(256), 0, stream>>>(x, W1, B1, W2, B2, W3, B3, out);
}

// Round 4
// 128.804 us; speedup vs baseline: 1.0175x; 1.0175x over previous
//
#include <hip/hip_runtime.h>

// Problem constants (KANLayer): B=1024, I=128, O=128, H=5
#define Bsz 1024
#define Isz 128
#define Osz 128
#define Hsz 5
#define PSTRIDE 48   // packed per-edge param record: 46 floats + 2 pad (192 B, 16B aligned)
#define ICHUNK 16    // i-slice per block -> 8 partial-sum rounds per (b,o)

// ---------------------------------------------------------------------------
// Prologue: gather the 6 param arrays into one aligned [O*I][48] record so the
// main loop's wave-uniform param fetch becomes 3x s_load_dwordx16.
// (Measured ~free: total-vs-kernel gap identical with/without it R1-R3.)
// ---------------------------------------------------------------------------
__global__ __launch_bounds__(256)
void repack_kernel(const float* __restrict__ W1, const float* __restrict__ B1,
                   const float* __restrict__ W2, const float* __restrict__ B2,
                   const float* __restrict__ W3, const float* __restrict__ B3,
                   float* __restrict__ P) {
    int idx = blockIdx.x * 256 + threadIdx.x;   // e*48 + s
    if (idx >= Osz * Isz * PSTRIDE) return;
    int e = idx / PSTRIDE;
    int s = idx - e * PSTRIDE;
    float v = 0.0f;
    if (s < 5)        v = W1[e * 5 + s];
    else if (s < 10)  v = B1[e * 5 + (s - 5)];
    else if (s < 35)  v = W2[e * 25 + (s - 10)];
    else if (s < 40)  v = B2[e * 5 + (s - 35)];
    else if (s < 45)  v = W3[e * 5 + (s - 40)];
    else if (s == 45) v = B3[e];
    P[idx] = v;
}

// ---------------------------------------------------------------------------
// Main kernel (round-2 structure = best known, + latency fixes).
// Block = (o, batch-tile 256, i-chunk 16); thread owns one (b,o).
//  - all 16 x-values preloaded to registers (VMEM waits out of inner loop)
//  - 16-edge loop fully unrolled so s_load_dwordx16 params hoist/pipeline
//  - grid 4096 blocks (16/CU queued, 8/CU resident), launch_bounds(256,8)
// Params wave-uniform -> scalar loads (confirmed R2: VGPR=24).
// ---------------------------------------------------------------------------
__global__ __launch_bounds__(256, 8)
void kan_kernel(const float* __restrict__ x, const float* __restrict__ P,
                float* __restrict__ out) {
    const int tid = threadIdx.x;
    const int o   = blockIdx.x & (Osz - 1);                 // fastest: 128 blocks share x-tile
    const int ic  = (blockIdx.x >> 7) & (Isz / ICHUNK - 1); // 0..7
    const int b0  = (blockIdx.x >> 10) * 256;               // 0..3 batch tile
    const int i0  = ic * ICHUNK;
    const int b   = b0 + tid;

    // Own x slice: 16 floats, 64B-aligned, loaded once.
    float4 xq[ICHUNK / 4];
    const float4* xv = (const float4*)(x + (size_t)b * Isz + i0);
    #pragma unroll
    for (int j = 0; j < ICHUNK / 4; ++j) xq[j] = xv[j];
    const float* xf = (const float*)xq;

    const float* __restrict__ pbase = P + (size_t)(o * Isz + i0) * PSTRIDE;

    float acc = 0.0f;

    #pragma unroll
    for (int il = 0; il < ICHUNK; ++il) {
        const float* __restrict__ pp = pbase + il * PSTRIDE;

        // Wave-uniform packed param record (46 floats) -> 3x s_load_dwordx16.
        float w1[Hsz], b1[Hsz], w2[Hsz * Hsz], b2[Hsz], w3[Hsz];
        #pragma unroll
        for (int h = 0; h < Hsz; ++h) { w1[h] = pp[h]; b1[h] = pp[5 + h]; }
        #pragma unroll
        for (int j = 0; j < Hsz * Hsz; ++j) w2[j] = pp[10 + j];
        #pragma unroll
        for (int h = 0; h < Hsz; ++h) { b2[h] = pp[35 + h]; w3[h] = pp[40 + h]; }
        const float b3v = pp[45];

        const float a = xf[il];

        // layer 1: scalar -> H, leaky_relu(0.01)
        float h1[Hsz];
        #pragma unroll
        for (int h = 0; h < Hsz; ++h) {
            float v = fmaf(a, w1[h], b1[h]);
            h1[h] = fmaxf(v, 0.01f * v);
        }
        // layer 2 (H->H, lrelu) + layer 3 (H->1)
        float y = b3v;
        #pragma unroll
        for (int k = 0; k < Hsz; ++k) {
            float s = b2[k];
            #pragma unroll
            for (int h = 0; h < Hsz; ++h)
                s = fmaf(h1[h], w2[k * Hsz + h], s);
            s = fmaxf(s, 0.01f * s);
            y = fmaf(s, w3[k], y);
        }
        acc += y;
    }

    // One fp32 atomic per thread (out pre-zeroed by memset).
    atomicAdd(&out[(size_t)b * Osz + o], acc);
}

extern "C" void kernel_launch(void* const* d_in, const int* in_sizes, int n_in,
                              void* d_out, int out_size, void* d_ws, size_t ws_size,
                              hipStream_t stream) {
    const float* x  = (const float*)d_in[0];
    const float* W1 = (const float*)d_in[1];
    const float* B1 = (const float*)d_in[2];
    const float* W2 = (const float*)d_in[3];
    const float* B2 = (const float*)d_in[4];
    const float* W3 = (const float*)d_in[5];
    const float* B3 = (const float*)d_in[6];
    float* out = (float*)d_out;
    float* P   = (float*)d_ws;   // 3 MiB packed params (ws re-poisoned each call)

    // Repack params every call (d_ws is re-poisoned before every launch).
    const int n = Osz * Isz * PSTRIDE;
    repack_kernel<<<dim3((n + 255) / 256), dim3(256), 0, stream>>>(W1, B1, W2, B2, W3, B3, P);

    // out accumulates 8 i-chunk partials via atomicAdd -> must start at zero.
    hipMemsetAsync(out, 0, (size_t)out_size * sizeof(float), stream);

    const dim3 grid(Osz * (Isz / ICHUNK) * (Bsz / 256));  // 4096 blocks
    kan_kernel<<<grid, dim3(256), 0, stream>>>(x, P, out);
}

// Round 5
// 96.953 us; speedup vs baseline: 1.3518x; 1.3285x over previous
//
#include <hip/hip_runtime.h>

// Problem constants (KANLayer): B=1024, I=128, O=128, H=5
#define Bsz 1024
#define Isz 128
#define Osz 128
#define Hsz 5
#define PSTRIDE 48   // packed per-edge param record: 46 floats + 2 pad (192 B, 16B aligned)
#define GB 64        // batches per block (batch-group)
#define NG (Bsz / GB)

// ---------------------------------------------------------------------------
// Prologue: gather the 6 param arrays into one aligned [O*I][48] record so the
// per-thread one-time param load is 12 clean dwordx4.
// ---------------------------------------------------------------------------
__global__ __launch_bounds__(256)
void repack_kernel(const float* __restrict__ W1, const float* __restrict__ B1,
                   const float* __restrict__ W2, const float* __restrict__ B2,
                   const float* __restrict__ W3, const float* __restrict__ B3,
                   float* __restrict__ P) {
    int idx = blockIdx.x * 256 + threadIdx.x;   // e*48 + s
    if (idx >= Osz * Isz * PSTRIDE) return;
    int e = idx / PSTRIDE;
    int s = idx - e * PSTRIDE;
    float v = 0.0f;
    if (s < 5)        v = W1[e * 5 + s];
    else if (s < 10)  v = B1[e * 5 + (s - 5)];
    else if (s < 35)  v = W2[e * 25 + (s - 10)];
    else if (s < 40)  v = B2[e * 5 + (s - 35)];
    else if (s < 45)  v = W3[e * 5 + (s - 40)];
    else if (s == 45) v = B3[e];
    P[idx] = v;
}

// ---------------------------------------------------------------------------
// Edge-stationary main kernel.
// Thread <-> one edge (o,i); its 46 params live in VGPRs for the whole kernel
// (loaded once). Batches stream through LDS. Per batch: 55 all-VGPR VALU ops
// + 6-step shfl_xor reduce over the wave's 64 i's; reduced value parked in
// lane bl. Epilogue combines the two i-half waves via 1 KB LDS and stores
// each out element exactly once (no atomics, no memset).
// Block = 4 waves = 2 o's x 128 i. Grid = 64 o-pairs x 16 batch-groups
// = 1024 blocks = 4/CU (LDS 33 KB caps at 4/CU anyway).
// ---------------------------------------------------------------------------
__global__ __launch_bounds__(256, 4)
void kan_kernel(const float* __restrict__ x, const float* __restrict__ P,
                float* __restrict__ out) {
    __shared__ float xs[GB * Isz];        // 32 KB: x[b0:b0+64][0:128]
    __shared__ float partial[4 * 64];     // 1 KB: per-wave reduced rows

    const int tid = threadIdx.x;
    const int ob  = blockIdx.x & 63;      // o-pair index (fastest)
    const int g   = blockIdx.x >> 6;      // batch group
    const int b0  = g * GB;
    const int w   = tid >> 6;             // wave 0..3
    const int l   = tid & 63;             // lane
    const int o   = 2 * ob + (w >> 1);    // waves 0,1 -> o0; waves 2,3 -> o1
    const int i   = 64 * (w & 1) + l;     // i-half per wave

    // --- stage x tile (coalesced float4, once) ---
    {
        const float4* xg = (const float4*)(x + (size_t)b0 * Isz);
        float4* xs4 = (float4*)xs;
        #pragma unroll
        for (int j = 0; j < (GB * Isz / 4) / 256; ++j)   // 8 iters
            xs4[tid + 256 * j] = xg[tid + 256 * j];
    }

    // --- my edge's params -> VGPRs (12x dwordx4, once) ---
    float p[PSTRIDE];
    {
        const float4* pr = (const float4*)(P + (size_t)(o * Isz + i) * PSTRIDE);
        #pragma unroll
        for (int j = 0; j < PSTRIDE / 4; ++j)
            ((float4*)p)[j] = pr[j];
    }
    __syncthreads();

    float res = 0.0f;   // will hold out-partial for batch b0+l (this wave's i-half)

    for (int bl = 0; bl < GB; bl += 4) {
        // 4 independent batches in flight: ILP for FMA chains + overlapping
        // reduce chains.
        float a[4], y[4];
        #pragma unroll
        for (int u = 0; u < 4; ++u) a[u] = xs[(bl + u) * Isz + i];

        #pragma unroll
        for (int u = 0; u < 4; ++u) {
            // layer 1: scalar -> H, leaky_relu(0.01)
            float h1[Hsz];
            #pragma unroll
            for (int h = 0; h < Hsz; ++h) {
                float v = fmaf(a[u], p[h], p[5 + h]);
                h1[h] = fmaxf(v, 0.01f * v);
            }
            // layer 2 (H->H, lrelu) + layer 3 (H->1)
            float yy = p[45];
            #pragma unroll
            for (int k = 0; k < Hsz; ++k) {
                float s = p[35 + k];
                #pragma unroll
                for (int h = 0; h < Hsz; ++h)
                    s = fmaf(h1[h], p[10 + k * Hsz + h], s);
                s = fmaxf(s, 0.01f * s);
                yy = fmaf(s, p[40 + k], yy);
            }
            y[u] = yy;
        }

        // butterfly reduce over the wave's 64 i's; park result in lane bl+u
        #pragma unroll
        for (int u = 0; u < 4; ++u) {
            float s = y[u];
            #pragma unroll
            for (int m = 1; m <= 32; m <<= 1)
                s += __shfl_xor(s, m, 64);
            if (l == bl + u) res = s;
        }
    }

    partial[w * 64 + l] = res;
    __syncthreads();

    // combine i-half waves and store: 128 outputs per block, each written once
    if (tid < 128) {
        const int bl = tid & 63;
        const int oo = tid >> 6;
        const float v = partial[(2 * oo) * 64 + bl] + partial[(2 * oo + 1) * 64 + bl];
        out[(size_t)(b0 + bl) * Osz + (2 * ob + oo)] = v;
    }
}

extern "C" void kernel_launch(void* const* d_in, const int* in_sizes, int n_in,
                              void* d_out, int out_size, void* d_ws, size_t ws_size,
                              hipStream_t stream) {
    const float* x  = (const float*)d_in[0];
    const float* W1 = (const float*)d_in[1];
    const float* B1 = (const float*)d_in[2];
    const float* W2 = (const float*)d_in[3];
    const float* B2 = (const float*)d_in[4];
    const float* W3 = (const float*)d_in[5];
    const float* B3 = (const float*)d_in[6];
    float* out = (float*)d_out;
    float* P   = (float*)d_ws;   // 3 MiB packed params (ws re-poisoned each call)

    const int n = Osz * Isz * PSTRIDE;
    repack_kernel<<<dim3((n + 255) / 256), dim3(256), 0, stream>>>(W1, B1, W2, B2, W3, B3, P);

    const dim3 grid((Osz / 2) * NG);   // 64 o-pairs x 16 batch groups = 1024 blocks
    kan_kernel<<<grid, dim3(256), 0, stream>>>(x, P, out);
}

// Round 6
// 92.011 us; speedup vs baseline: 1.4244x; 1.0537x over previous
//
#include <hip/hip_runtime.h>

// Problem constants (KANLayer): B=1024, I=128, O=128, H=5
#define Bsz 1024
#define Isz 128
#define Osz 128
#define Hsz 5
#define GB 64    // batches per block (== lanes, for reduce parking)
#define NG (Bsz / GB)
#define UF 8     // batches in flight (independent MLP+reduce chains)

// ---------------------------------------------------------------------------
// DPP wave64 sum: quad_perm xor1, xor2, row_half_mirror, row_mirror,
// row_bcast:15, row_bcast:31. Full sum lands in lane 63. All VALU
// (GCNDPPCombine folds the dpp mov into v_add_f32_dpp), zero DS-pipe.
// ---------------------------------------------------------------------------
template <int CTRL>
__device__ __forceinline__ float dpp_add(float s) {
    int t = __builtin_amdgcn_update_dpp(0, __builtin_bit_cast(int, s),
                                        CTRL, 0xf, 0xf, true);
    return s + __builtin_bit_cast(float, t);
}
__device__ __forceinline__ float wave_sum64_lane63(float s) {
    s = dpp_add<0xB1>(s);    // quad_perm [1,0,3,2]  (xor 1)
    s = dpp_add<0x4E>(s);    // quad_perm [2,3,0,1]  (xor 2)
    s = dpp_add<0x141>(s);   // row_half_mirror      (xor 4)
    s = dpp_add<0x140>(s);   // row_mirror           (xor 8)
    s = dpp_add<0x142>(s);   // row_bcast:15  (rows 1,3 += row 0,2 sums)
    s = dpp_add<0x143>(s);   // row_bcast:31  (upper half += lower-half sum)
    return s;                // lane 63 holds the full 64-lane sum
}

// ---------------------------------------------------------------------------
// Edge-stationary kernel. Thread <-> one edge (o,i); 46 params gathered once
// into VGPRs directly from the raw arrays (no repack dispatch, no d_ws).
// Batches stream through LDS; per batch: ~56 all-VGPR VALU + DPP reduce
// (6 VALU, no DS) + readlane/cndmask park in lane bl. Epilogue combines the
// two i-half waves via 1 KB LDS; each out element written exactly once.
// Block = 4 waves = 2 o's x 128 i. Grid = 64 o-pairs x 16 batch groups
// = 1024 blocks (4/CU, LDS 33 KB caps at 4/CU).
// ---------------------------------------------------------------------------
__global__ __launch_bounds__(256, 4)
void kan_kernel(const float* __restrict__ x,
                const float* __restrict__ W1, const float* __restrict__ B1,
                const float* __restrict__ W2, const float* __restrict__ B2,
                const float* __restrict__ W3, const float* __restrict__ B3,
                float* __restrict__ out) {
    __shared__ float xs[GB * Isz];        // 32 KB: x[b0:b0+64][0:128]
    __shared__ float partial[4 * 64];     // 1 KB: per-wave reduced rows

    const int tid = threadIdx.x;
    const int ob  = blockIdx.x & 63;      // o-pair index (fastest)
    const int g   = blockIdx.x >> 6;      // batch group
    const int b0  = g * GB;
    const int w   = tid >> 6;             // wave 0..3
    const int l   = tid & 63;             // lane
    const int o   = 2 * ob + (w >> 1);    // waves 0,1 -> o0; waves 2,3 -> o1
    const int i   = 64 * (w & 1) + l;     // i-half per wave
    const int e   = o * Isz + i;

    // --- stage x tile (coalesced float4, once) ---
    {
        const float4* xg = (const float4*)(x + (size_t)b0 * Isz);
        float4* xs4 = (float4*)xs;
        #pragma unroll
        for (int j = 0; j < (GB * Isz / 4) / 256; ++j)   // 8 iters
            xs4[tid + 256 * j] = xg[tid + 256 * j];
    }

    // --- my edge's 46 params -> VGPRs, gathered once (one-time latency) ---
    float w1[Hsz], b1[Hsz], w2[Hsz * Hsz], b2[Hsz], w3[Hsz];
    #pragma unroll
    for (int h = 0; h < Hsz; ++h) {
        w1[h] = W1[(size_t)e * Hsz + h];
        b1[h] = B1[(size_t)e * Hsz + h];
        b2[h] = B2[(size_t)e * Hsz + h];
        w3[h] = W3[(size_t)e * Hsz + h];
    }
    #pragma unroll
    for (int j = 0; j < Hsz * Hsz; ++j) w2[j] = W2[(size_t)e * Hsz * Hsz + j];
    const float b3v = B3[e];

    __syncthreads();

    float res = 0.0f;   // out-partial for batch b0+l (this wave's i-half)

    for (int bl = 0; bl < GB; bl += UF) {
        float y[UF];
        #pragma unroll
        for (int u = 0; u < UF; ++u) {
            const float a = xs[(bl + u) * Isz + i];

            // layer 1: scalar -> H, leaky_relu(0.01)
            float h1[Hsz];
            #pragma unroll
            for (int h = 0; h < Hsz; ++h) {
                float v = fmaf(a, w1[h], b1[h]);
                h1[h] = fmaxf(v, 0.01f * v);
            }
            // layer 2 (H->H, lrelu) + layer 3 (H->1)
            float yy = b3v;
            #pragma unroll
            for (int k = 0; k < Hsz; ++k) {
                float s = b2[k];
                #pragma unroll
                for (int h = 0; h < Hsz; ++h)
                    s = fmaf(h1[h], w2[k * Hsz + h], s);
                s = fmaxf(s, 0.01f * s);
                yy = fmaf(s, w3[k], yy);
            }
            y[u] = yy;
        }

        // DPP reduce each chain; park lane-63 total in lane bl+u.
        #pragma unroll
        for (int u = 0; u < UF; ++u) {
            const float s = wave_sum64_lane63(y[u]);
            const float tot = __builtin_bit_cast(float,
                __builtin_amdgcn_readlane(__builtin_bit_cast(int, s), 63));
            if (l == bl + u) res = tot;
        }
    }

    partial[w * 64 + l] = res;
    __syncthreads();

    // combine i-half waves and store: 128 outputs per block, each written once
    if (tid < 128) {
        const int bl = tid & 63;
        const int oo = tid >> 6;
        const float v = partial[(2 * oo) * 64 + bl] + partial[(2 * oo + 1) * 64 + bl];
        out[(size_t)(b0 + bl) * Osz + (2 * ob + oo)] = v;
    }
}

extern "C" void kernel_launch(void* const* d_in, const int* in_sizes, int n_in,
                              void* d_out, int out_size, void* d_ws, size_t ws_size,
                              hipStream_t stream) {
    const float* x  = (const float*)d_in[0];
    const float* W1 = (const float*)d_in[1];
    const float* B1 = (const float*)d_in[2];
    const float* W2 = (const float*)d_in[3];
    const float* B2 = (const float*)d_in[4];
    const float* W3 = (const float*)d_in[5];
    const float* B3 = (const float*)d_in[6];
    float* out = (float*)d_out;

    const dim3 grid((Osz / 2) * NG);   // 64 o-pairs x 16 batch groups = 1024 blocks
    kan_kernel<<<grid, dim3(256), 0, stream>>>(x, W1, B1, W2, B2, W3, B3, out);
}

// Round 7
// 89.269 us; speedup vs baseline: 1.4682x; 1.0307x over previous
//
#include <hip/hip_runtime.h>

// Problem constants (KANLayer): B=1024, I=128, O=128, H=5
#define Bsz 1024
#define Isz 128
#define Osz 128
#define Hsz 5
#define GB 32    // batches per block (16.5 KB LDS -> no LDS occupancy cap)
#define NG (Bsz / GB)
#define UF 8     // batches in flight (independent MLP+reduce chains)

// ---------------------------------------------------------------------------
// DPP wave64 sum: quad_perm xor1, xor2, row_half_mirror, row_mirror,
// row_bcast:15, row_bcast:31. Full sum lands in lane 63. All VALU
// (GCNDPPCombine folds the dpp mov into v_add_f32_dpp), zero DS-pipe.
// ---------------------------------------------------------------------------
template <int CTRL>
__device__ __forceinline__ float dpp_add(float s) {
    int t = __builtin_amdgcn_update_dpp(0, __builtin_bit_cast(int, s),
                                        CTRL, 0xf, 0xf, true);
    return s + __builtin_bit_cast(float, t);
}
__device__ __forceinline__ float wave_sum64_lane63(float s) {
    s = dpp_add<0xB1>(s);    // quad_perm [1,0,3,2]  (xor 1)
    s = dpp_add<0x4E>(s);    // quad_perm [2,3,0,1]  (xor 2)
    s = dpp_add<0x141>(s);   // row_half_mirror      (xor 4)
    s = dpp_add<0x140>(s);   // row_mirror           (xor 8)
    s = dpp_add<0x142>(s);   // row_bcast:15
    s = dpp_add<0x143>(s);   // row_bcast:31
    return s;                // lane 63 holds the full 64-lane sum
}

// ---------------------------------------------------------------------------
// Edge-stationary kernel (R5/R6 structure, occupancy raised).
// Thread <-> one edge (o,i); 46 params live in VGPRs (gathered once).
// GB=32 batches stream through 16.5 KB LDS -> grid 2048 blocks and
// launch_bounds(256,6) give 6 waves/SIMD (was 4, VALUBusy ~53%).
// b3 contribution is batch-invariant -> wave-reduced once, added at the end.
// Block = 4 waves = 2 o's x 128 i. Each out element written exactly once.
// ---------------------------------------------------------------------------
__global__ __launch_bounds__(256, 6)
void kan_kernel(const float* __restrict__ x,
                const float* __restrict__ W1, const float* __restrict__ B1,
                const float* __restrict__ W2, const float* __restrict__ B2,
                const float* __restrict__ W3, const float* __restrict__ B3,
                float* __restrict__ out) {
    __shared__ float xs[GB * Isz];        // 16 KB: x[b0:b0+32][0:128]
    __shared__ float partial[4 * GB];     // 512 B: per-wave reduced rows

    const int tid = threadIdx.x;
    const int ob  = blockIdx.x & 63;      // o-pair index (fastest)
    const int g   = blockIdx.x >> 6;      // batch group 0..31
    const int b0  = g * GB;
    const int w   = tid >> 6;             // wave 0..3
    const int l   = tid & 63;             // lane
    const int o   = 2 * ob + (w >> 1);    // waves 0,1 -> o0; waves 2,3 -> o1
    const int i   = 64 * (w & 1) + l;     // i-half per wave
    const int e   = o * Isz + i;

    // --- stage x tile (coalesced float4, once) ---
    {
        const float4* xg = (const float4*)(x + (size_t)b0 * Isz);
        float4* xs4 = (float4*)xs;
        #pragma unroll
        for (int j = 0; j < (GB * Isz / 4) / 256; ++j)   // 4 iters
            xs4[tid + 256 * j] = xg[tid + 256 * j];
    }

    // --- my edge's 46 params -> VGPRs, gathered once (one-time latency) ---
    float w1[Hsz], b1[Hsz], w2[Hsz * Hsz], b2[Hsz], w3[Hsz];
    #pragma unroll
    for (int h = 0; h < Hsz; ++h) {
        w1[h] = W1[(size_t)e * Hsz + h];
        b1[h] = B1[(size_t)e * Hsz + h];
        b2[h] = B2[(size_t)e * Hsz + h];
        w3[h] = W3[(size_t)e * Hsz + h];
    }
    #pragma unroll
    for (int j = 0; j < Hsz * Hsz; ++j) w2[j] = W2[(size_t)e * Hsz * Hsz + j];

    // batch-invariant b3 term: sum over this wave's 64 i's, once
    const float s3w = wave_sum64_lane63(B3[e]);
    const float s3  = __builtin_bit_cast(float,
        __builtin_amdgcn_readlane(__builtin_bit_cast(int, s3w), 63));

    __syncthreads();

    float res = 0.0f;   // out-partial for batch b0+l (l < GB), this i-half

    #pragma unroll
    for (int bl = 0; bl < GB; bl += UF) {
        float y[UF];
        #pragma unroll
        for (int u = 0; u < UF; ++u) {
            const float a = xs[(bl + u) * Isz + i];

            // layer 1: scalar -> H, leaky_relu(0.01)
            float h1[Hsz];
            #pragma unroll
            for (int h = 0; h < Hsz; ++h) {
                float v = fmaf(a, w1[h], b1[h]);
                h1[h] = fmaxf(v, 0.01f * v);
            }
            // layer 2 (H->H, lrelu) + layer 3 (H->1, b3 hoisted out)
            float yy = 0.0f;
            #pragma unroll
            for (int k = 0; k < Hsz; ++k) {
                float s = b2[k];
                #pragma unroll
                for (int h = 0; h < Hsz; ++h)
                    s = fmaf(h1[h], w2[k * Hsz + h], s);
                s = fmaxf(s, 0.01f * s);
                yy = fmaf(s, w3[k], yy);
            }
            y[u] = yy;
        }

        // DPP reduce each chain; park lane-63 total in lane bl+u.
        #pragma unroll
        for (int u = 0; u < UF; ++u) {
            const float s = wave_sum64_lane63(y[u]);
            const float tot = __builtin_bit_cast(float,
                __builtin_amdgcn_readlane(__builtin_bit_cast(int, s), 63));
            if (l == bl + u) res = tot;
        }
    }

    if (l < GB) partial[w * GB + l] = res + s3;
    __syncthreads();

    // combine i-half waves and store: 64 outputs per block, each written once
    if (tid < 2 * GB) {
        const int bl = tid & (GB - 1);
        const int oo = tid >> 5;
        const float v = partial[(2 * oo) * GB + bl] + partial[(2 * oo + 1) * GB + bl];
        out[(size_t)(b0 + bl) * Osz + (2 * ob + oo)] = v;
    }
}

extern "C" void kernel_launch(void* const* d_in, const int* in_sizes, int n_in,
                              void* d_out, int out_size, void* d_ws, size_t ws_size,
                              hipStream_t stream) {
    const float* x  = (const float*)d_in[0];
    const float* W1 = (const float*)d_in[1];
    const float* B1 = (const float*)d_in[2];
    const float* W2 = (const float*)d_in[3];
    const float* B2 = (const float*)d_in[4];
    const float* W3 = (const float*)d_in[5];
    const float* B3 = (const float*)d_in[6];
    float* out = (float*)d_out;

    const dim3 grid((Osz / 2) * NG);   // 64 o-pairs x 32 batch groups = 2048 blocks
    kan_kernel<<<grid, dim3(256), 0, stream>>>(x, W1, B1, W2, B2, W3, B3, out);
}

// Round 8
// 89.013 us; speedup vs baseline: 1.4724x; 1.0029x over previous
//
#include <hip/hip_runtime.h>

// Problem constants (KANLayer): B=1024, I=128, O=128, H=5
#define Bsz 1024
#define Isz 128
#define Osz 128
#define Hsz 5
#define GB 32    // batches per block (16.5 KB LDS -> up to 9 blocks/CU)
#define NG (Bsz / GB)
#define UF 4     // batches in flight; 46 params + 4 chains ~= 78 live VGPRs < 84
                 // (UF=8 needed ~100 live regs -> spills/serialization under the
                 //  (256,6) cap; that's why R7 only gained 3 us)

// ---------------------------------------------------------------------------
// DPP wave64 sum: quad_perm xor1, xor2, row_half_mirror, row_mirror,
// row_bcast:15, row_bcast:31. Full sum lands in lane 63. All VALU
// (GCNDPPCombine folds the dpp mov into v_add_f32_dpp), zero DS-pipe.
// ---------------------------------------------------------------------------
template <int CTRL>
__device__ __forceinline__ float dpp_add(float s) {
    int t = __builtin_amdgcn_update_dpp(0, __builtin_bit_cast(int, s),
                                        CTRL, 0xf, 0xf, true);
    return s + __builtin_bit_cast(float, t);
}
__device__ __forceinline__ float wave_sum64_lane63(float s) {
    s = dpp_add<0xB1>(s);    // quad_perm [1,0,3,2]  (xor 1)
    s = dpp_add<0x4E>(s);    // quad_perm [2,3,0,1]  (xor 2)
    s = dpp_add<0x141>(s);   // row_half_mirror      (xor 4)
    s = dpp_add<0x140>(s);   // row_mirror           (xor 8)
    s = dpp_add<0x142>(s);   // row_bcast:15
    s = dpp_add<0x143>(s);   // row_bcast:31
    return s;                // lane 63 holds the full 64-lane sum
}

// ---------------------------------------------------------------------------
// Edge-stationary kernel. Thread <-> one edge (o,i); 46 params in VGPRs
// (gathered once, latency overlapped by co-resident blocks). GB=32 batches
// stream through LDS; per batch ~56 all-VGPR VALU + DPP reduce. UF=4 keeps
// the live set under the (256,6) VGPR cap so we get 6 waves/SIMD AND clean
// 4-chain ILP. Block = 4 waves = 2 o's x 128 i; grid 2048 blocks.
// Each out element written exactly once (no atomics, no memset).
// ---------------------------------------------------------------------------
__global__ __launch_bounds__(256, 6)
void kan_kernel(const float* __restrict__ x,
                const float* __restrict__ W1, const float* __restrict__ B1,
                const float* __restrict__ W2, const float* __restrict__ B2,
                const float* __restrict__ W3, const float* __restrict__ B3,
                float* __restrict__ out) {
    __shared__ float xs[GB * Isz];        // 16 KB: x[b0:b0+32][0:128]
    __shared__ float partial[4 * GB];     // 512 B: per-wave reduced rows

    const int tid = threadIdx.x;
    const int ob  = blockIdx.x & 63;      // o-pair index (fastest)
    const int g   = blockIdx.x >> 6;      // batch group 0..31
    const int b0  = g * GB;
    const int w   = tid >> 6;             // wave 0..3
    const int l   = tid & 63;             // lane
    const int o   = 2 * ob + (w >> 1);    // waves 0,1 -> o0; waves 2,3 -> o1
    const int i   = 64 * (w & 1) + l;     // i-half per wave
    const int e   = o * Isz + i;

    // --- stage x tile (coalesced float4, once) ---
    {
        const float4* xg = (const float4*)(x + (size_t)b0 * Isz);
        float4* xs4 = (float4*)xs;
        #pragma unroll
        for (int j = 0; j < (GB * Isz / 4) / 256; ++j)   // 4 iters
            xs4[tid + 256 * j] = xg[tid + 256 * j];
    }

    // --- my edge's 46 params -> VGPRs, gathered once ---
    float w1[Hsz], b1[Hsz], w2[Hsz * Hsz], b2[Hsz], w3[Hsz];
    #pragma unroll
    for (int h = 0; h < Hsz; ++h) {
        w1[h] = W1[(size_t)e * Hsz + h];
        b1[h] = B1[(size_t)e * Hsz + h];
        b2[h] = B2[(size_t)e * Hsz + h];
        w3[h] = W3[(size_t)e * Hsz + h];
    }
    #pragma unroll
    for (int j = 0; j < Hsz * Hsz; ++j) w2[j] = W2[(size_t)e * Hsz * Hsz + j];

    // batch-invariant b3 term: sum over this wave's 64 i's, once
    const float s3w = wave_sum64_lane63(B3[e]);
    const float s3  = __builtin_bit_cast(float,
        __builtin_amdgcn_readlane(__builtin_bit_cast(int, s3w), 63));

    __syncthreads();

    float res = 0.0f;   // out-partial for batch b0+l (l < GB), this i-half

    #pragma unroll
    for (int bl = 0; bl < GB; bl += UF) {
        float y[UF];
        #pragma unroll
        for (int u = 0; u < UF; ++u) {
            const float a = xs[(bl + u) * Isz + i];

            // layer 1: scalar -> H, leaky_relu(0.01)
            float h1[Hsz];
            #pragma unroll
            for (int h = 0; h < Hsz; ++h) {
                float v = fmaf(a, w1[h], b1[h]);
                h1[h] = fmaxf(v, 0.01f * v);
            }
            // layer 2 (H->H, lrelu) + layer 3 (H->1, b3 hoisted out)
            float yy = 0.0f;
            #pragma unroll
            for (int k = 0; k < Hsz; ++k) {
                float s = b2[k];
                #pragma unroll
                for (int h = 0; h < Hsz; ++h)
                    s = fmaf(h1[h], w2[k * Hsz + h], s);
                s = fmaxf(s, 0.01f * s);
                yy = fmaf(s, w3[k], yy);
            }
            y[u] = yy;
        }

        // DPP reduce each chain; park lane-63 total in lane bl+u.
        #pragma unroll
        for (int u = 0; u < UF; ++u) {
            const float s = wave_sum64_lane63(y[u]);
            const float tot = __builtin_bit_cast(float,
                __builtin_amdgcn_readlane(__builtin_bit_cast(int, s), 63));
            if (l == bl + u) res = tot;
        }
    }

    if (l < GB) partial[w * GB + l] = res + s3;
    __syncthreads();

    // combine i-half waves and store: 64 outputs per block, each written once
    if (tid < 2 * GB) {
        const int bl = tid & (GB - 1);
        const int oo = tid >> 5;
        const float v = partial[(2 * oo) * GB + bl] + partial[(2 * oo + 1) * GB + bl];
        out[(size_t)(b0 + bl) * Osz + (2 * ob + oo)] = v;
    }
}

extern "C" void kernel_launch(void* const* d_in, const int* in_sizes, int n_in,
                              void* d_out, int out_size, void* d_ws, size_t ws_size,
                              hipStream_t stream) {
    const float* x  = (const float*)d_in[0];
    const float* W1 = (const float*)d_in[1];
    const float* B1 = (const float*)d_in[2];
    const float* W2 = (const float*)d_in[3];
    const float* B2 = (const float*)d_in[4];
    const float* W3 = (const float*)d_in[5];
    const float* B3 = (const float*)d_in[6];
    float* out = (float*)d_out;

    const dim3 grid((Osz / 2) * NG);   // 64 o-pairs x 32 batch groups = 2048 blocks
    kan_kernel<<<grid, dim3(256), 0, stream>>>(x, W1, B1, W2, B2, W3, B3, out);
}